// Round 7
// baseline (8448.924 us; speedup 1.0000x reference)
//
#include <hip/hip_runtime.h>
#include <math.h>

#define B 512
#define S 256
#define D 64
#define H 512
#define BH (B*H)

typedef __attribute__((ext_vector_type(8))) short short8;
typedef __attribute__((ext_vector_type(4))) float f32x4;

__device__ inline unsigned short f2bf(float v) {            // fp32 -> bf16 RNE
    unsigned int u = __float_as_uint(v);
    unsigned int r = (u + 0x7fffu + ((u >> 16) & 1u)) >> 16;
    return (unsigned short)r;
}
__device__ inline float bf2f(unsigned short b) {
    return __uint_as_float(((unsigned int)b) << 16);
}

__global__ __launch_bounds__(256) void init_zero(
    float* __restrict__ h32, float* __restrict__ c32,
    unsigned short* __restrict__ hHi, unsigned short* __restrict__ hLo)
{
    int i = blockIdx.x * blockDim.x + threadIdx.x;
    if (i < BH) {
        h32[i] = 0.f;
        c32[i] = 0.f;
        hHi[i] = 0;
        hLo[i] = 0;
    }
}

// Pre-split Whh/Wih -> bf16 hi/lo fragment slabs. grid (64 jt, 9 kb), 256 thr.
// Slab per (jt,kb): [half2][ks2][cg4][jj32][8] shorts = 4096 shorts (8 KB).
// j global = jt*32 + jj, encoded j = u*4 + q  (u = unit, q = gate).
__global__ __launch_bounds__(256) void prep_weights(
    const float* __restrict__ Whh, const float* __restrict__ Wih,
    unsigned short* __restrict__ wswz)
{
    const int jt = blockIdx.x;
    const int kb = blockIdx.y;
    const int t = threadIdx.x;
    const int jj = t >> 3;          // 0..31
    const int kk8 = t & 7;          // 0..7 (8-k group)
    const int jg = jt*32 + jj;
    const int u = jg >> 2, q = jg & 3;
    const int Wrow = q*H + u;

    const float* src = (kb < 8) ? (Whh + (size_t)Wrow*H + kb*64 + kk8*8)
                                : (Wih + (size_t)Wrow*D + kk8*8);
    float v[8];
    *(float4*)&v[0] = *(const float4*)(src);
    *(float4*)&v[4] = *(const float4*)(src + 4);

    unsigned short hi[8], lo[8];
    #pragma unroll
    for (int e = 0; e < 8; ++e) {
        hi[e] = f2bf(v[e]);
        lo[e] = f2bf(v[e] - bf2f(hi[e]));
    }
    const int ks = kk8 >> 2, cg = kk8 & 3;
    const size_t slab = (size_t)(jt*9 + kb) * 4096;
    const size_t oH = slab + (size_t)(0*2048 + ks*1024 + cg*256 + jj*8);
    const size_t oL = slab + (size_t)(1*2048 + ks*1024 + cg*256 + jj*8);
    *(short8*)(wswz + oH) = *(const short8*)hi;
    *(short8*)(wswz + oL) = *(const short8*)lo;
}

// Attention gate — round-2 structure (measured 4.8us). One WG per 2 rows.
__global__ __launch_bounds__(256) void attn_kernel(
    const float* __restrict__ x, const float* __restrict__ Wa,
    const float* __restrict__ Ua, const float* __restrict__ ba,
    const float* __restrict__ Va,
    const float* __restrict__ h32, const float* __restrict__ c32,
    unsigned short* __restrict__ xHi, unsigned short* __restrict__ xLo, int t)
{
    const int d = threadIdx.x & 63;
    const int r = (threadIdx.x >> 6) & 1;
    const int p = threadIdx.x >> 7;
    const int b = blockIdx.x * 2 + r;

    const int rd = t & 1;
    const float* __restrict__ hrow = h32 + (size_t)rd*BH + (size_t)b*H;
    const float* __restrict__ crow = c32 + (size_t)b*H;
    const float* __restrict__ xrow = x + ((size_t)b*S + t)*D;

    __shared__ float part[2][2][64];
    __shared__ float ta[2][64];
    __shared__ float pv[2][2][64];

    float a = 0.f;
    if (p == 0) {
        a = ba[d];
        #pragma unroll 8
        for (int k = 0; k < D; ++k) a += xrow[k] * Wa[k*D + d];
        #pragma unroll 8
        for (int k = 0; k < H; ++k) a += hrow[k] * Ua[k*D + d];
    } else {
        #pragma unroll 8
        for (int k = 0; k < H; ++k) a += crow[k] * Ua[(size_t)(H + k)*D + d];
    }
    part[r][p][d] = a;
    __syncthreads();
    if (p == 0) {
        ta[r][d] = tanhf(part[r][0][d] + part[r][1][d]);
    }
    __syncthreads();
    float av = 0.f;
    {
        const int k0 = p * 32;
        #pragma unroll 8
        for (int k = k0; k < k0 + 32; ++k) av += ta[r][k] * Va[k*D + d];
    }
    pv[r][p][d] = av;
    __syncthreads();
    float v = pv[r][0][d] + pv[r][1][d];
    float m = v;
    #pragma unroll
    for (int o = 32; o > 0; o >>= 1) m = fmaxf(m, __shfl_xor(m, o));
    float e = expf(v - m);
    float ssum = e;
    #pragma unroll
    for (int o = 32; o > 0; o >>= 1) ssum += __shfl_xor(ssum, o);
    if (p == 0) {
        float val = (e / ssum) * xrow[d];
        unsigned short hi = f2bf(val);
        unsigned short lo = f2bf(val - bf2f(hi));
        xHi[(size_t)b*D + d] = hi;
        xLo[(size_t)b*D + d] = lo;
    }
}

// Gate GEMM (bf16-split 3-pass MFMA) + fused LSTM update.
// grid (64 jt, 8 rt) = 512 WGs (2/CU). Tile: 64 rows x 32 j. 4 waves 2x2:
// wr = row half (32 rows), wc = j half (16 cols). Wave = 2 mfma tiles (rb 0/1).
// All fragments are NAMED registers (no arrays -> no scratch risk).
__global__ __launch_bounds__(256, 2) void gates_kernel(
    const unsigned short* __restrict__ wswz,
    const unsigned short* __restrict__ hHi, const unsigned short* __restrict__ hLo,
    const unsigned short* __restrict__ xHi, const unsigned short* __restrict__ xLo,
    float* __restrict__ h32, float* __restrict__ c32,
    const float* __restrict__ bih, const float* __restrict__ bhh, int t)
{
    const int tid = threadIdx.x;
    const int lane = tid & 63;
    const int wid = tid >> 6;
    const int wr = wid >> 1, wc = wid & 1;
    const int jt = blockIdx.x;
    const int b0 = blockIdx.y * 64;
    const int l15 = lane & 15;
    const int cg = lane >> 4;

    __shared__ __align__(16) unsigned short aHi[2][64][72];
    __shared__ __align__(16) unsigned short aLo[2][64][72];
    __shared__ float gout[64][37];

    const int rd = t & 1, wrs = rd ^ 1;
    const unsigned short* __restrict__ hHiR = hHi + (size_t)rd*BH;
    const unsigned short* __restrict__ hLoR = hLo + (size_t)rd*BH;

    const int srow = tid >> 2;      // 0..63
    const int q4 = tid & 3;         // 16-short col group

    // prologue: stage chunk 0 into buf 0
    {
        const size_t base = (size_t)(b0 + srow)*H + q4*16;
        *(short8*)&aHi[0][srow][q4*16]     = *(const short8*)(hHiR + base);
        *(short8*)&aHi[0][srow][q4*16 + 8] = *(const short8*)(hHiR + base + 8);
        *(short8*)&aLo[0][srow][q4*16]     = *(const short8*)(hLoR + base);
        *(short8*)&aLo[0][srow][q4*16 + 8] = *(const short8*)(hLoR + base + 8);
    }
    __syncthreads();

    f32x4 acc0 = {0,0,0,0}, acc1 = {0,0,0,0};
    const int lofs = cg*256 + (wc*16 + l15)*8;

    for (int kb = 0; kb < 9; ++kb) {
        const int cur = kb & 1;
        // B fragments for this chunk (global, swizzled, coalesced)
        const unsigned short* pB = wswz + (size_t)(jt*9 + kb)*4096;
        short8 bh0 = *(const short8*)(pB + 0*2048 + 0*1024 + lofs);
        short8 bh1 = *(const short8*)(pB + 0*2048 + 1*1024 + lofs);
        short8 bl0 = *(const short8*)(pB + 1*2048 + 0*1024 + lofs);
        short8 bl1 = *(const short8*)(pB + 1*2048 + 1*1024 + lofs);
        // prefetch-stage next chunk into buf cur^1
        if (kb < 8) {
            const unsigned short *sh, *sl;
            if (kb + 1 < 8) {
                const size_t base = (size_t)(b0 + srow)*H + (kb + 1)*64 + q4*16;
                sh = hHiR + base; sl = hLoR + base;
            } else {
                const size_t base = (size_t)(b0 + srow)*D + q4*16;
                sh = xHi + base; sl = xLo + base;
            }
            *(short8*)&aHi[cur^1][srow][q4*16]     = *(const short8*)sh;
            *(short8*)&aHi[cur^1][srow][q4*16 + 8] = *(const short8*)(sh + 8);
            *(short8*)&aLo[cur^1][srow][q4*16]     = *(const short8*)sl;
            *(short8*)&aLo[cur^1][srow][q4*16 + 8] = *(const short8*)(sl + 8);
        }
        // A fragments from buf cur (conflict-free: 8-lane phases span 32 banks)
        const int ar = wr*32 + l15;
        short8 ah00 = *(const short8*)&aHi[cur][ar     ][cg*8];
        short8 ah01 = *(const short8*)&aHi[cur][ar     ][32 + cg*8];
        short8 ah10 = *(const short8*)&aHi[cur][ar + 16][cg*8];
        short8 ah11 = *(const short8*)&aHi[cur][ar + 16][32 + cg*8];
        short8 al00 = *(const short8*)&aLo[cur][ar     ][cg*8];
        short8 al01 = *(const short8*)&aLo[cur][ar     ][32 + cg*8];
        short8 al10 = *(const short8*)&aLo[cur][ar + 16][cg*8];
        short8 al11 = *(const short8*)&aLo[cur][ar + 16][32 + cg*8];

        acc0 = __builtin_amdgcn_mfma_f32_16x16x32_bf16(ah00, bh0, acc0, 0,0,0);
        acc1 = __builtin_amdgcn_mfma_f32_16x16x32_bf16(ah10, bh0, acc1, 0,0,0);
        acc0 = __builtin_amdgcn_mfma_f32_16x16x32_bf16(ah00, bl0, acc0, 0,0,0);
        acc1 = __builtin_amdgcn_mfma_f32_16x16x32_bf16(ah10, bl0, acc1, 0,0,0);
        acc0 = __builtin_amdgcn_mfma_f32_16x16x32_bf16(al00, bh0, acc0, 0,0,0);
        acc1 = __builtin_amdgcn_mfma_f32_16x16x32_bf16(al10, bh0, acc1, 0,0,0);
        acc0 = __builtin_amdgcn_mfma_f32_16x16x32_bf16(ah01, bh1, acc0, 0,0,0);
        acc1 = __builtin_amdgcn_mfma_f32_16x16x32_bf16(ah11, bh1, acc1, 0,0,0);
        acc0 = __builtin_amdgcn_mfma_f32_16x16x32_bf16(ah01, bl1, acc0, 0,0,0);
        acc1 = __builtin_amdgcn_mfma_f32_16x16x32_bf16(ah11, bl1, acc1, 0,0,0);
        acc0 = __builtin_amdgcn_mfma_f32_16x16x32_bf16(al01, bh1, acc0, 0,0,0);
        acc1 = __builtin_amdgcn_mfma_f32_16x16x32_bf16(al11, bh1, acc1, 0,0,0);
        __syncthreads();
    }

    {   // D layout: row = cg*4 + r, col = l15 within each 16x16 tile
        const int m0 = cg * 4;
        #pragma unroll
        for (int r = 0; r < 4; ++r) {
            gout[wr*32 + m0 + r     ][wc*16 + l15] = acc0[r];
            gout[wr*32 + 16 + m0 + r][wc*16 + l15] = acc1[r];
        }
    }
    __syncthreads();
    {   // fused LSTM update: 64 rows x 8 units; thread -> (u8, 2 rows)
        const int u8 = tid & 7;
        const int u_glob = jt*8 + u8;
        const float bs0 = bih[0*H + u_glob] + bhh[0*H + u_glob];
        const float bs1 = bih[1*H + u_glob] + bhh[1*H + u_glob];
        const float bs2 = bih[2*H + u_glob] + bhh[2*H + u_glob];
        const float bs3 = bih[3*H + u_glob] + bhh[3*H + u_glob];
        float* __restrict__ h32w = h32 + (size_t)wrs*BH;
        unsigned short* __restrict__ hHiW = (unsigned short*)hHi + (size_t)wrs*BH;
        unsigned short* __restrict__ hLoW = (unsigned short*)hLo + (size_t)wrs*BH;
        #pragma unroll
        for (int pp = 0; pp < 2; ++pp) {
            const int row_loc = (tid >> 3) + pp*32;
            const int b = b0 + row_loc;
            float gi = gout[row_loc][u8*4 + 0] + bs0;
            float gf = gout[row_loc][u8*4 + 1] + bs1;
            float gg = gout[row_loc][u8*4 + 2] + bs2;
            float go = gout[row_loc][u8*4 + 3] + bs3;
            const size_t idx = (size_t)b*H + u_glob;
            float c_old = c32[idx];
            float si = 1.f/(1.f + expf(-gi));
            float sf = 1.f/(1.f + expf(-gf));
            float so = 1.f/(1.f + expf(-go));
            float cn = sf*c_old + si*tanhf(gg);
            float hn = so*tanhf(cn);
            c32[idx] = cn;
            h32w[idx] = hn;
            unsigned short hi = f2bf(hn);
            unsigned short lo = f2bf(hn - bf2f(hi));
            hHiW[idx] = hi;
            hLoW[idx] = lo;
        }
    }
}

__global__ __launch_bounds__(256) void fc_kernel(
    const float* __restrict__ fcw, const float* __restrict__ fcb,
    const float* __restrict__ h32, float* __restrict__ out)
{
    const int b = blockIdx.x;
    __shared__ float hrow[H];
    const float* __restrict__ hp = h32 + (size_t)b*H;   // final h in slot 0 (S even)
    for (int k = threadIdx.x; k < H; k += 256) hrow[k] = hp[k];
    __syncthreads();
    int j = threadIdx.x;
    if (j < 24) {
        float a = fcb[j];
        #pragma unroll 8
        for (int k = 0; k < H; ++k) a += hrow[k] * fcw[j*H + k];
        out[b*24 + j] = a;
    }
}

extern "C" void kernel_launch(void* const* d_in, const int* in_sizes, int n_in,
                              void* d_out, int out_size, void* d_ws, size_t ws_size,
                              hipStream_t stream) {
    const float* x   = (const float*)d_in[0];
    const float* Wa  = (const float*)d_in[1];
    const float* Ua  = (const float*)d_in[2];
    const float* ba  = (const float*)d_in[3];
    const float* Va  = (const float*)d_in[4];
    const float* Wih = (const float*)d_in[5];
    const float* Whh = (const float*)d_in[6];
    const float* bih = (const float*)d_in[7];
    const float* bhh = (const float*)d_in[8];
    const float* fcw = (const float*)d_in[9];
    const float* fcb = (const float*)d_in[10];
    float* out = (float*)d_out;

    char* base = (char*)d_ws;
    float* h32 = (float*)(base);                                    // 2*BH f32
    float* c32 = (float*)(base + (size_t)2*BH*4);                   // BH f32
    unsigned short* hHi = (unsigned short*)(base + (size_t)3*BH*4); // 2*BH
    unsigned short* hLo = hHi + (size_t)2*BH;                       // 2*BH
    unsigned short* xHi = hLo + (size_t)2*BH;                       // B*D
    unsigned short* xLo = xHi + (size_t)B*D;                        // B*D
    unsigned short* wswz = xLo + (size_t)B*D;                       // 576*4096

    hipLaunchKernelGGL(init_zero, dim3((BH + 255)/256), dim3(256), 0, stream,
                       h32, c32, hHi, hLo);
    hipLaunchKernelGGL(prep_weights, dim3(64, 9), dim3(256), 0, stream,
                       Whh, Wih, wswz);
    for (int t = 0; t < S; ++t) {
        hipLaunchKernelGGL(attn_kernel, dim3(B/2), dim3(256), 0, stream,
                           x, Wa, Ua, ba, Va, h32, c32, xHi, xLo, t);
        hipLaunchKernelGGL(gates_kernel, dim3(64, 8), dim3(256), 0, stream,
                           wswz, hHi, hLo, xHi, xLo, h32, c32, bih, bhh, t);
    }
    hipLaunchKernelGGL(fc_kernel, dim3(B), dim3(256), 0, stream, fcw, fcb, h32, out);
}